// Round 1
// baseline (465.771 us; speedup 1.0000x reference)
//
#include <hip/hip_runtime.h>
#include <hip/hip_bf16.h>
#include <math.h>

#define HN 8
#define DM 512
#define DHD 64
#define FFD 2048
#define BB 2
#define SS 4096
#define MT (BB*SS)   // 8192 token rows

typedef __bf16 bf16_t;
typedef __bf16 bf16x8 __attribute__((ext_vector_type(8)));
typedef __bf16 bf16x4 __attribute__((ext_vector_type(4)));
typedef float  floatx4 __attribute__((ext_vector_type(4)));

// Async global->LDS, 16B per lane. HW semantics: wave-uniform base + lane*16
// (m104/m108), so lds ptr computed as base + lane*16 works as intended.
__device__ __forceinline__ void async_copy16(const bf16_t* g, bf16_t* l) {
  __builtin_amdgcn_global_load_lds((const __attribute__((address_space(1))) void*)g,
                                   (__attribute__((address_space(3))) void*)l,
                                   16, 0, 0);
}

__device__ __forceinline__ float gelu_f(float x) {
  return 0.5f * x * (1.0f + erff(x * 0.70710678118654752f));
}

// ---------------- LayerNorm: fp32 in -> bf16 out, fused gamma/beta ----------
__global__ __launch_bounds__(256)
void ln_kernel(const float* __restrict__ x, const float* __restrict__ g,
               const float* __restrict__ be, bf16_t* __restrict__ out)
{
  const int row = blockIdx.x, t = threadIdx.x;
  const float* xr = x + (size_t)row * DM;
  float v0 = xr[t], v1 = xr[t + 256];
  float s = v0 + v1, s2 = v0 * v0 + v1 * v1;
#pragma unroll
  for (int o = 32; o > 0; o >>= 1) { s += __shfl_down(s, o); s2 += __shfl_down(s2, o); }
  __shared__ float red[8];
  if ((t & 63) == 0) { red[(t >> 6) * 2] = s; red[(t >> 6) * 2 + 1] = s2; }
  __syncthreads();
  float ts  = red[0] + red[2] + red[4] + red[6];
  float ts2 = red[1] + red[3] + red[5] + red[7];
  float mu = ts * (1.0f / DM);
  float rv = rsqrtf(ts2 * (1.0f / DM) - mu * mu + 1e-5f);
  out[(size_t)row * DM + t]       = (bf16_t)((v0 - mu) * rv * g[t]       + be[t]);
  out[(size_t)row * DM + t + 256] = (bf16_t)((v1 - mu) * rv * g[t + 256] + be[t + 256]);
}

// ------------- Weight prep: fp32 [K,N] -> bf16 [N,K] (transpose+convert) ----
__global__ __launch_bounds__(256)
void transpose_bf16(const float* __restrict__ src, bf16_t* __restrict__ dst,
                    const int K, const int N)
{
  __shared__ float tile[32][33];
  const int n0 = blockIdx.x * 32, k0 = blockIdx.y * 32;
  const int tx = threadIdx.x & 31, ty = threadIdx.x >> 5;
#pragma unroll
  for (int i = 0; i < 32; i += 8)
    tile[ty + i][tx] = src[(size_t)(k0 + ty + i) * N + n0 + tx];
  __syncthreads();
#pragma unroll
  for (int i = 0; i < 32; i += 8)
    dst[(size_t)(n0 + ty + i) * K + k0 + tx] = (bf16_t)tile[tx][ty + i];
}

// ---------------- GEMM: C[M,N] = A[M,K] * Bt[N,K]^T, bf16 MFMA --------------
// 128x128 tile, BK=32, 4 waves in 2x2, each wave 64x64 (4x4 mfma blocks).
// XOR-swizzled LDS so ds_read_b128 stays bank-even with global_load_lds staging.
// EPI: 0 = bf16 row-major; 1 = bf16 transposed (ld=ldt); 2 = f32 gelu(acc+bias)+res;
//      3 = bf16 gelu(acc+bias); 4 = f32 acc+bias+res
template <int EPI>
__global__ __launch_bounds__(256)
void gemm_bt(const bf16_t* __restrict__ A, const bf16_t* __restrict__ Bt,
             const int M, const int N, const int K,
             const float* __restrict__ bias, const float* __restrict__ res,
             bf16_t* __restrict__ outb, float* __restrict__ outf, const int ldt)
{
  __shared__ __align__(16) bf16_t lA[128 * 32];
  __shared__ __align__(16) bf16_t lB[128 * 32];
  const int tid = threadIdx.x;
  const int wave = tid >> 6, lane = tid & 63;
  const int wm = wave & 1, wn = wave >> 1;
  const int quad = lane >> 4, l16 = lane & 15;
  const int swz = quad ^ (l16 & 3) ^ ((l16 >> 2) & 3); // per-lane constant

  int sr[2], sc[2];
#pragma unroll
  for (int i = 0; i < 2; ++i) {
    int p = tid + 256 * i;
    int r = p >> 2;
    sr[i] = r;
    sc[i] = 8 * ((p & 3) ^ (r & 3) ^ ((r >> 2) & 3));
  }
  const bf16_t* Ab = A + (size_t)(blockIdx.x * 128) * K;
  const bf16_t* Bb = Bt + (size_t)(blockIdx.y * 128) * K;

  const floatx4 vzero = {0.f, 0.f, 0.f, 0.f};
  floatx4 acc[4][4];
#pragma unroll
  for (int i = 0; i < 4; ++i)
#pragma unroll
    for (int j = 0; j < 4; ++j) acc[i][j] = vzero;

  for (int k0 = 0; k0 < K; k0 += 32) {
    __syncthreads();
#pragma unroll
    for (int i = 0; i < 2; ++i) {
      async_copy16(Ab + (size_t)sr[i] * K + k0 + sc[i], lA + (tid + 256 * i) * 8);
      async_copy16(Bb + (size_t)sr[i] * K + k0 + sc[i], lB + (tid + 256 * i) * 8);
    }
    __syncthreads();
    bf16x8 af[4], bfv[4];
#pragma unroll
    for (int i = 0; i < 4; ++i)
      af[i] = *(const bf16x8*)(lA + (wm * 64 + i * 16 + l16) * 32 + swz * 8);
#pragma unroll
    for (int j = 0; j < 4; ++j)
      bfv[j] = *(const bf16x8*)(lB + (wn * 64 + j * 16 + l16) * 32 + swz * 8);
#pragma unroll
    for (int i = 0; i < 4; ++i)
#pragma unroll
      for (int j = 0; j < 4; ++j)
        acc[i][j] = __builtin_amdgcn_mfma_f32_16x16x32_bf16(af[i], bfv[j], acc[i][j], 0, 0, 0);
  }

  const int m00 = blockIdx.x * 128 + wm * 64;
  const int n00 = blockIdx.y * 128 + wn * 64;
#pragma unroll
  for (int i = 0; i < 4; ++i) {
#pragma unroll
    for (int j = 0; j < 4; ++j) {
      const int m0 = m00 + i * 16 + quad * 4;     // C/D: row=quad*4+reg, col=l16
      const int n  = n00 + j * 16 + l16;
      floatx4 v = acc[i][j];
      if (EPI == 0) {
#pragma unroll
        for (int r = 0; r < 4; ++r) outb[(size_t)(m0 + r) * N + n] = (bf16_t)v[r];
      } else if (EPI == 1) {
        bf16x4 pk = {(bf16_t)v[0], (bf16_t)v[1], (bf16_t)v[2], (bf16_t)v[3]};
        *(bf16x4*)(outb + (size_t)n * ldt + m0) = pk;   // contiguous 8B store
      } else if (EPI == 2) {
        const float bb = bias[n];
#pragma unroll
        for (int r = 0; r < 4; ++r)
          outf[(size_t)(m0 + r) * N + n] = gelu_f(v[r] + bb) + res[(size_t)(m0 + r) * N + n];
      } else if (EPI == 3) {
        const float bb = bias[n];
#pragma unroll
        for (int r = 0; r < 4; ++r)
          outb[(size_t)(m0 + r) * N + n] = (bf16_t)gelu_f(v[r] + bb);
      } else {
        const float bb = bias[n];
#pragma unroll
        for (int r = 0; r < 4; ++r)
          outf[(size_t)(m0 + r) * N + n] = v[r] + bb + res[(size_t)(m0 + r) * N + n];
      }
    }
  }
}

// ---------------- Flash attention -------------------------------------------
// grid (S/128, H, B); 4 waves, each owns 32 Q-rows -> softmax stats wave-local.
// K/V staged to LDS (XOR swizzle); P goes C-layout -> LDS -> A-operand layout.
__global__ __launch_bounds__(256, 2)
void attn_kernel(const bf16_t* __restrict__ qm, const bf16_t* __restrict__ km,
                 const bf16_t* __restrict__ vtm, const int* __restrict__ mask,
                 bf16_t* __restrict__ ctx)
{
  const int b = blockIdx.z, h = blockIdx.y;
  const int q0 = blockIdx.x * 128;
  const int tid = threadIdx.x;
  const int wave = tid >> 6, lane = tid & 63;
  const int quad = lane >> 4, l16 = lane & 15;

  __shared__ __align__(16) bf16_t lK[128 * DHD];      // [key][dh]
  __shared__ __align__(16) bf16_t lV[DHD * 128];      // [dh][key] (from vt)
  __shared__ __align__(16) bf16_t lP[4][32 * 128];    // per-wave P, swizzled

  const size_t qrow0 = (size_t)b * SS + q0;
  bf16x8 qa[2][2];
#pragma unroll
  for (int mb = 0; mb < 2; ++mb)
#pragma unroll
    for (int c = 0; c < 2; ++c)
      qa[mb][c] = *(const bf16x8*)(qm + (qrow0 + wave * 32 + mb * 16 + l16) * DM
                                   + h * DHD + c * 32 + quad * 8);

  const floatx4 vzero = {0.f, 0.f, 0.f, 0.f};
  const floatx4 vneg  = {-1e30f, -1e30f, -1e30f, -1e30f};
  float m_run[2][4], l_run[2][4];
  floatx4 cacc[2][4];
#pragma unroll
  for (int mb = 0; mb < 2; ++mb) {
#pragma unroll
    for (int r = 0; r < 4; ++r) { m_run[mb][r] = -1e30f; l_run[mb][r] = 0.0f; }
#pragma unroll
    for (int nb = 0; nb < 4; ++nb) cacc[mb][nb] = vzero;
  }

  const int* maskb = mask + b * SS;
  const bf16_t* Kb = km + (size_t)b * SS * DM + h * DHD;
  const bf16_t* Vb = vtm + (size_t)(h * DHD) * MT + (size_t)b * SS;
  bf16_t* lPw = lP[wave];

  for (int s0 = 0; s0 < SS; s0 += 128) {
    __syncthreads();
#pragma unroll
    for (int i = 0; i < 4; ++i) {
      int p = tid + 256 * i;
      int key = p >> 3;
      int cs = (p & 7) ^ (key & 7);
      async_copy16(Kb + (size_t)(s0 + key) * DM + cs * 8, lK + p * 8);
      int dh = p >> 4;
      int cs2 = (p & 15) ^ (dh & 7);
      async_copy16(Vb + (size_t)dh * MT + s0 + cs2 * 8, lV + p * 8);
    }
    __syncthreads();

    // ---- S = Q K^T (per wave: 32 q-rows x 128 keys) ----
    floatx4 sacc[2][8];
#pragma unroll
    for (int mb = 0; mb < 2; ++mb)
#pragma unroll
      for (int j = 0; j < 8; ++j) sacc[mb][j] = vzero;
#pragma unroll
    for (int j = 0; j < 8; ++j) {
      int key = j * 16 + l16;
#pragma unroll
      for (int c = 0; c < 2; ++c) {
        int chunk = c * 4 + quad;
        bf16x8 kf = *(const bf16x8*)(lK + (key * 8 + (chunk ^ (key & 7))) * 8);
        sacc[0][j] = __builtin_amdgcn_mfma_f32_16x16x32_bf16(qa[0][c], kf, sacc[0][j], 0, 0, 0);
        sacc[1][j] = __builtin_amdgcn_mfma_f32_16x16x32_bf16(qa[1][c], kf, sacc[1][j], 0, 0, 0);
      }
    }

    int mv[8];
#pragma unroll
    for (int j = 0; j < 8; ++j) mv[j] = maskb[s0 + j * 16 + l16];

    // ---- online softmax (rows = quad*4+r within each 16-block) ----
#pragma unroll
    for (int mb = 0; mb < 2; ++mb) {
      float mt[4] = {-1e30f, -1e30f, -1e30f, -1e30f};
#pragma unroll
      for (int j = 0; j < 8; ++j) {
        floatx4 sv = sacc[mb][j] * 0.125f;   // 1/sqrt(64)
        if (mv[j] == 0) sv = vneg;
        sacc[mb][j] = sv;
#pragma unroll
        for (int r = 0; r < 4; ++r) mt[r] = fmaxf(mt[r], sv[r]);
      }
#pragma unroll
      for (int o = 1; o < 16; o <<= 1)
#pragma unroll
        for (int r = 0; r < 4; ++r) mt[r] = fmaxf(mt[r], __shfl_xor(mt[r], o));
      float al[4], rs[4] = {0.f, 0.f, 0.f, 0.f};
#pragma unroll
      for (int r = 0; r < 4; ++r) {
        float mn = fmaxf(m_run[mb][r], mt[r]);
        al[r] = __expf(m_run[mb][r] - mn);
        m_run[mb][r] = mn;
      }
#pragma unroll
      for (int j = 0; j < 8; ++j)
#pragma unroll
        for (int r = 0; r < 4; ++r) {
          float pv = __expf(sacc[mb][j][r] - m_run[mb][r]);
          rs[r] += pv;
          int row = mb * 16 + quad * 4 + r;
          int col = j * 16 + l16;
          lPw[row * 128 + (((col >> 3) ^ (row & 7)) << 3) + (col & 7)] = (bf16_t)pv;
        }
#pragma unroll
      for (int o = 1; o < 16; o <<= 1)
#pragma unroll
        for (int r = 0; r < 4; ++r) rs[r] += __shfl_xor(rs[r], o);
#pragma unroll
      for (int r = 0; r < 4; ++r) l_run[mb][r] = l_run[mb][r] * al[r] + rs[r];
#pragma unroll
      for (int nb = 0; nb < 4; ++nb)
#pragma unroll
        for (int r = 0; r < 4; ++r) cacc[mb][nb][r] *= al[r];
    }
    __syncthreads();

    // ---- ctx += P V ----
#pragma unroll
    for (int kc = 0; kc < 4; ++kc) {
      bf16x8 pa[2];
#pragma unroll
      for (int mb = 0; mb < 2; ++mb) {
        int row = mb * 16 + l16;
        int chunk = kc * 4 + quad;
        pa[mb] = *(const bf16x8*)(lPw + (row * 16 + (chunk ^ (row & 7))) * 8);
      }
#pragma unroll
      for (int nb = 0; nb < 4; ++nb) {
        int dh = nb * 16 + l16;
        int chunk = kc * 4 + quad;
        bf16x8 vf = *(const bf16x8*)(lV + (dh * 16 + (chunk ^ (dh & 7))) * 8);
        cacc[0][nb] = __builtin_amdgcn_mfma_f32_16x16x32_bf16(pa[0], vf, cacc[0][nb], 0, 0, 0);
        cacc[1][nb] = __builtin_amdgcn_mfma_f32_16x16x32_bf16(pa[1], vf, cacc[1][nb], 0, 0, 0);
      }
    }
  }

#pragma unroll
  for (int mb = 0; mb < 2; ++mb)
#pragma unroll
    for (int r = 0; r < 4; ++r) {
      float inv = 1.0f / l_run[mb][r];
      size_t row = qrow0 + wave * 32 + mb * 16 + quad * 4 + r;
#pragma unroll
      for (int nb = 0; nb < 4; ++nb)
        ctx[row * DM + h * DHD + nb * 16 + l16] = (bf16_t)(cacc[mb][nb][r] * inv);
    }
}

// ---------------------------------------------------------------------------
extern "C" void kernel_launch(void* const* d_in, const int* in_sizes, int n_in,
                              void* d_out, int out_size, void* d_ws, size_t ws_size,
                              hipStream_t stream)
{
  (void)in_sizes; (void)n_in; (void)out_size; (void)ws_size;
  const float* reaction = (const float*)d_in[0];
  const int*   mask     = (const int*)d_in[1];
  const float* Wq = (const float*)d_in[2];
  const float* Wk = (const float*)d_in[3];
  const float* Wv = (const float*)d_in[4];
  const float* Wo = (const float*)d_in[5];
  const float* bo = (const float*)d_in[6];
  const float* W1 = (const float*)d_in[7];
  const float* b1 = (const float*)d_in[8];
  const float* W2 = (const float*)d_in[9];
  const float* b2 = (const float*)d_in[10];
  const float* g_sa = (const float*)d_in[11];
  const float* b_sa = (const float*)d_in[12];
  const float* g_ff = (const float*)d_in[13];
  const float* b_ff = (const float*)d_in[14];
  float* out = (float*)d_out;

  char* ws = (char*)d_ws;
  size_t off = 0;
  auto take = [&](size_t bytes) -> char* {
    char* p = ws + off;
    off += (bytes + 255) & ~(size_t)255;
    return p;
  };

  bf16_t* xln = (bf16_t*)take((size_t)MT * DM * 2);    // LN1 out; reused as y (LN2 out)
  bf16_t* WqT = (bf16_t*)take((size_t)DM * DM * 2);
  bf16_t* WkT = (bf16_t*)take((size_t)DM * DM * 2);
  bf16_t* WvT = (bf16_t*)take((size_t)DM * DM * 2);
  bf16_t* WoT = (bf16_t*)take((size_t)DM * DM * 2);
  bf16_t* W1T = (bf16_t*)take((size_t)FFD * DM * 2);
  bf16_t* W2T = (bf16_t*)take((size_t)DM * FFD * 2);
  bf16_t* qb  = (bf16_t*)take((size_t)MT * DM * 2);    // qb..ctx contiguous 32MB,
  bf16_t* kb  = (bf16_t*)take((size_t)MT * DM * 2);    // reused as FFN hidden h
  bf16_t* vtb = (bf16_t*)take((size_t)DM * MT * 2);    // V transposed [D, M]
  bf16_t* ctx = (bf16_t*)take((size_t)MT * DM * 2);
  float*  x2  = (float*)take((size_t)MT * DM * 4);
  bf16_t* yb  = xln;
  bf16_t* hb  = qb;   // 8192*2048 bf16 = 32MB over qb/kb/vtb/ctx (all dead by then)

  // LN1 + weight prep
  ln_kernel<<<MT, 256, 0, stream>>>(reaction, g_sa, b_sa, xln);
  transpose_bf16<<<dim3(16, 16), 256, 0, stream>>>(Wq, WqT, DM, DM);
  transpose_bf16<<<dim3(16, 16), 256, 0, stream>>>(Wk, WkT, DM, DM);
  transpose_bf16<<<dim3(16, 16), 256, 0, stream>>>(Wv, WvT, DM, DM);
  transpose_bf16<<<dim3(16, 16), 256, 0, stream>>>(Wo, WoT, DM, DM);
  transpose_bf16<<<dim3(64, 16), 256, 0, stream>>>(W1, W1T, DM, FFD);
  transpose_bf16<<<dim3(16, 64), 256, 0, stream>>>(W2, W2T, FFD, DM);

  // QKV projections (V stored transposed for the PV B-operand)
  gemm_bt<0><<<dim3(64, 4), 256, 0, stream>>>(xln, WqT, MT, DM, DM, nullptr, nullptr, qb, nullptr, 0);
  gemm_bt<0><<<dim3(64, 4), 256, 0, stream>>>(xln, WkT, MT, DM, DM, nullptr, nullptr, kb, nullptr, 0);
  gemm_bt<1><<<dim3(64, 4), 256, 0, stream>>>(xln, WvT, MT, DM, DM, nullptr, nullptr, vtb, nullptr, MT);

  // Flash attention
  attn_kernel<<<dim3(SS / 128, HN, BB), 256, 0, stream>>>(qb, kb, vtb, mask, ctx);

  // Output projection + GELU + residual -> x2 (fp32)
  gemm_bt<2><<<dim3(64, 4), 256, 0, stream>>>(ctx, WoT, MT, DM, DM, bo, reaction, nullptr, x2, 0);

  // FFN
  ln_kernel<<<MT, 256, 0, stream>>>(x2, g_ff, b_ff, yb);
  gemm_bt<3><<<dim3(64, 16), 256, 0, stream>>>(yb, W1T, MT, FFD, DM, b1, nullptr, hb, nullptr, 0);
  gemm_bt<4><<<dim3(64, 4), 256, 0, stream>>>(hb, W2T, MT, DM, FFD, b2, x2, nullptr, out, 0);
}